// Round 9
// baseline (483.805 us; speedup 1.0000x reference)
//
#include <hip/hip_runtime.h>
#include <hip/hip_bf16.h>
#include <math.h>

// Problem constants
#define M_ 2048
#define K_ 1024
#define V_ 50000
#define VP_ 50048        // V padded to 128
#define CV_ 120
#define NC_ (V_ + CV_)   // 50120 out row stride
#define S_ 100
#define B_ 32
#define PAD_IDX_ 1

// GEMM tiling: block 256x128, 4 waves stacked in M, wave tile 64x128
#define BM 256
#define BN 128
#define BK 32
#define NKT (K_ / BK)                   // 32 k-steps
#define NB_ (VP_ / BN)                  // 391 N-blocks
#define NMT (M_ / BM)                   // 8 M-blocks
#define NWG_ (NMT * NB_)                // 3128 = 8 * 391
#define WPX_ (NWG_ / 8)                 // 391 (exact)
#define BUFE 12288                      // bf16 elems per pipeline buf (24 KB)
#define ELS 132                         // Els row stride (ushorts), 66 words

// merged pre-kernel block ranges
#define WT_BLKS (782 * 16)              // 12512
#define PREP_BLKS (M_ / 4)              // 512
#define IDS_BLKS (((S_ * B_) + 255) / 256) // 13

typedef float f32x4 __attribute__((ext_vector_type(4)));
typedef float f32x16 __attribute__((ext_vector_type(16)));
typedef __bf16 bf16x8 __attribute__((ext_vector_type(8)));
typedef unsigned short ushort;

__device__ __forceinline__ void async_copy16(const void* g, void* l) {
    __builtin_amdgcn_global_load_lds(
        (const __attribute__((address_space(1))) void*)g,
        (__attribute__((address_space(3))) void*)l, 16, 0, 0);
}
// quarter-wave conflict-free chunk swizzle (verified r4: conflicts -> 0)
#define SIG(row) (((row) >> 1) & 3)

// ---------------------------------------------------------------------------
// merged pre-pass: [0,WT_BLKS) W-transpose; [WT,+PREP) hidden->bf16 + copy
// gate; [+PREP,+IDS) one-hot -> ids.
__global__ __launch_bounds__(256)
void k_pre(const float* __restrict__ W, __bf16* __restrict__ Wt,
           const float* __restrict__ hidden, const float* __restrict__ w_copy,
           const float* __restrict__ b_copy, __bf16* __restrict__ Ab,
           float* __restrict__ cvec, const float* __restrict__ src_map,
           int* __restrict__ ids)
{
    int bx = blockIdx.x;
    int tid = threadIdx.x;
    if (bx < WT_BLKS) {
        // ---- W [K][V] fp32 -> Wt [VP][K] bf16 (64x64 tile transpose)
        __shared__ __bf16 t[64][72];
        int v0 = (bx % 782) * 64;
        int k0 = (bx / 782) * 64;
        int kr = tid >> 4;
        int vq = tid & 15;
        int v4 = v0 + vq * 4;
#pragma unroll
        for (int i = 0; i < 4; ++i) {
            int k = k0 + kr + i * 16;
            f32x4 val = {};
            if (v4 < V_) val = *(const f32x4*)(W + (size_t)k * V_ + v4);
#pragma unroll
            for (int c = 0; c < 4; ++c) t[vq * 4 + c][kr + i * 16] = (__bf16)val[c];
        }
        __syncthreads();
        int vr = tid >> 2;
        int q  = tid & 3;
        __bf16* dst = Wt + (size_t)(v0 + vr) * K_ + k0;
#pragma unroll
        for (int i = 0; i < 2; ++i) {
            bf16x8 o;
#pragma unroll
            for (int e = 0; e < 8; ++e) o[e] = t[vr][q * 8 + i * 32 + e];
            *(bf16x8*)(dst + q * 8 + i * 32) = o;
        }
    } else if (bx < WT_BLKS + PREP_BLKS) {
        // ---- hidden->bf16 + copy gate. 1 wave per row.
        int n = (bx - WT_BLKS) * 4 + (tid >> 6);
        int lane = tid & 63;
        const float* h = hidden + (size_t)n * K_;
        __bf16* arow = Ab + (size_t)n * K_;
        float s = 0.f;
#pragma unroll
        for (int g = 0; g < 2; ++g) {
            int gg = 2 * lane + g;
            f32x4 a = *(const f32x4*)(h + gg * 8);
            f32x4 b = *(const f32x4*)(h + gg * 8 + 4);
            f32x4 wa = *(const f32x4*)(w_copy + gg * 8);
            f32x4 wb = *(const f32x4*)(w_copy + gg * 8 + 4);
            s += a[0]*wa[0] + a[1]*wa[1] + a[2]*wa[2] + a[3]*wa[3]
               + b[0]*wb[0] + b[1]*wb[1] + b[2]*wb[2] + b[3]*wb[3];
            bf16x8 v;
            v[0]=(__bf16)a[0]; v[1]=(__bf16)a[1]; v[2]=(__bf16)a[2]; v[3]=(__bf16)a[3];
            v[4]=(__bf16)b[0]; v[5]=(__bf16)b[1]; v[6]=(__bf16)b[2]; v[7]=(__bf16)b[3];
            *(bf16x8*)(arow + gg * 8) = v;
        }
#pragma unroll
        for (int off = 32; off; off >>= 1) s += __shfl_down(s, off);
        if (lane == 0) cvec[n] = 1.f / (1.f + __expf(-(s + b_copy[0])));
    } else {
        // ---- one-hot src_map -> integer ids [S*B]
        int i = (bx - WT_BLKS - PREP_BLKS) * 256 + tid;
        if (i < S_ * B_) {
            const float* r = src_map + (size_t)i * CV_;
            int id = 0;
            for (int v = 0; v < CV_; ++v)
                if (r[v] > 0.5f) { id = v; break; }
            ids[i] = id;
        }
    }
}

// ---------------------------------------------------------------------------
// GEMM: e = exp(A.Wt^T + b) (PAD col->0); bf16 E store; coalesced row partials.
// 3-buf pipeline (fully unrolled), counted vmcnt(6), raw s_barrier, setprio,
// 32x32x16 MFMA, 2-sub-phase body. Epilogue: no cross-lane ops (LDS reduce).
template<bool E16>
__global__ __launch_bounds__(256, 2)
void k_gemm_exp(const __bf16* __restrict__ A, const __bf16* __restrict__ Bt,
                const float* __restrict__ bias, float* __restrict__ out,
                ushort* __restrict__ E, float* __restrict__ part2)
{
    __shared__ __bf16 lds[3 * BUFE];   // 3 bufs x (A 16KB + B 8KB) = 72 KB

    const int tid  = threadIdx.x;
    const int lane = tid & 63;
    const int wid  = tid >> 6;

    // bijective XCD swizzle: 3128 = 8 * 391
    int orig = blockIdx.y * NMT + blockIdx.x;
    int nid  = (orig & 7) * WPX_ + (orig >> 3);
    const int m0 = (nid & 7) * BM;    // m fastest within an XCD's chunk
    const int nb = nid >> 3;
    const int n0 = nb * BN;

    f32x16 acc[2][4] = {};

#define STAGE_A(d, kt)                                                        \
    do {                                                                      \
        _Pragma("unroll")                                                     \
        for (int j = 0; j < 4; ++j) {                                         \
            int g = j * 256 + tid; int row = g >> 2;                          \
            int ch = (g & 3) ^ SIG(row);                                      \
            async_copy16(A + (size_t)(m0 + row) * K_ + (kt) * BK + ch * 8,    \
                         &lds[(d) * BUFE + (j * 256 + wid * 64) * 8]);        \
        }                                                                     \
    } while (0)
#define STAGE_B(d, kt)                                                        \
    do {                                                                      \
        _Pragma("unroll")                                                     \
        for (int j = 0; j < 2; ++j) {                                         \
            int g = j * 256 + tid; int row = g >> 2;                          \
            int ch = (g & 3) ^ SIG(row);                                      \
            async_copy16(Bt + (size_t)(n0 + row) * K_ + (kt) * BK + ch * 8,   \
                         &lds[(d) * BUFE + 8192 + (j * 256 + wid * 64) * 8]); \
        }                                                                     \
    } while (0)

    STAGE_A(0, 0); STAGE_B(0, 0);
    STAGE_A(1, 1); STAGE_B(1, 1);

    // 32x32x16 fragment addressing: row = tile + (lane&31), k-block = lane>>5
    const int rA  = lane & 31;
    const int kb  = lane >> 5;
    const int sig = (lane >> 1) & 3;

#pragma unroll
    for (int kt = 0; kt < NKT; ++kt) {
        const int cur = kt % 3;
        const int nxt = (kt + 2) % 3;
        __builtin_amdgcn_sched_barrier(0);
        if (kt < NKT - 1) asm volatile("s_waitcnt vmcnt(6)" ::: "memory");
        else              asm volatile("s_waitcnt vmcnt(0)" ::: "memory");
        __builtin_amdgcn_s_barrier();           // S_kt landed; buf(kt-1) reads done
        __builtin_amdgcn_sched_barrier(0);
        const __bf16* bufA = &lds[cur * BUFE];
        const __bf16* bufB = bufA + 8192;
        bf16x8 fa[2][2], fb[4][2];
        // ---- sub-phase 1: fa + fb[0] reads, A-stage, 4 MFMA
#pragma unroll
        for (int mt = 0; mt < 2; ++mt)
#pragma unroll
            for (int kk = 0; kk < 2; ++kk)
                fa[mt][kk] = *(const bf16x8*)(
                    &bufA[(wid * 64 + mt * 32 + rA) * BK + ((kk * 2 + kb) ^ sig) * 8]);
#pragma unroll
        for (int kk = 0; kk < 2; ++kk)
            fb[0][kk] = *(const bf16x8*)(
                &bufB[(0 * 32 + rA) * BK + ((kk * 2 + kb) ^ sig) * 8]);
        if (kt < NKT - 2) STAGE_A(nxt, kt + 2);
        __builtin_amdgcn_s_setprio(1);
#pragma unroll
        for (int mt = 0; mt < 2; ++mt)
#pragma unroll
            for (int kk = 0; kk < 2; ++kk)
                acc[mt][0] = __builtin_amdgcn_mfma_f32_32x32x16_bf16(
                    fa[mt][kk], fb[0][kk], acc[mt][0], 0, 0, 0);
        __builtin_amdgcn_s_setprio(0);
        __builtin_amdgcn_sched_barrier(0);      // keep sub-phase 2 below
        // ---- sub-phase 2: fb[1..3] reads, B-stage, 12 MFMA
#pragma unroll
        for (int nt = 1; nt < 4; ++nt)
#pragma unroll
            for (int kk = 0; kk < 2; ++kk)
                fb[nt][kk] = *(const bf16x8*)(
                    &bufB[(nt * 32 + rA) * BK + ((kk * 2 + kb) ^ sig) * 8]);
        if (kt < NKT - 2) STAGE_B(nxt, kt + 2);
        __builtin_amdgcn_s_setprio(1);
#pragma unroll
        for (int mt = 0; mt < 2; ++mt)
#pragma unroll
            for (int nt = 1; nt < 4; ++nt)
#pragma unroll
                for (int kk = 0; kk < 2; ++kk)
                    acc[mt][nt] = __builtin_amdgcn_mfma_f32_32x32x16_bf16(
                        fa[mt][kk], fb[nt][kk], acc[mt][nt], 0, 0, 0);
        __builtin_amdgcn_s_setprio(0);
    }
#undef STAGE_A
#undef STAGE_B

    __builtin_amdgcn_s_barrier();   // main loop fully done before LDS reuse

    // epilogue phase 1: bias + exp + reg psum; stage Els; coalesced E stores.
    // C/D layout (verified m74/m101): col = lane&31, row = (r&3)+8*(r>>2)+4*(lane>>5)
    const int rbase = m0 + wid * 64;
    const int rhi   = (lane >> 5) * 4;
    float psum[2][16];
#pragma unroll
    for (int mt = 0; mt < 2; ++mt)
#pragma unroll
        for (int r = 0; r < 16; ++r) psum[mt][r] = 0.f;
    ushort* Els = (ushort*)lds + wid * 64 * ELS;
#pragma unroll
    for (int nt = 0; nt < 4; ++nt) {
        int gcol = n0 + nt * 32 + rA;
        bool live = (gcol < V_) && (gcol != PAD_IDX_);
        float bb = (gcol < V_) ? bias[gcol] : 0.f;
#pragma unroll
        for (int mt = 0; mt < 2; ++mt) {
#pragma unroll
            for (int r = 0; r < 16; ++r) {
                int crow = (r & 3) + 8 * (r >> 2) + rhi;
                float e = live ? __expf(acc[mt][nt][r] + bb) : 0.f;
                psum[mt][r] += e;
                if (E16) {
                    __bf16 h = (__bf16)e;
                    Els[(mt * 32 + crow) * ELS + nt * 32 + rA] = *(const ushort*)&h;
                } else {
                    int grow = rbase + mt * 32 + crow;
                    if (gcol < V_) out[(size_t)grow * NC_ + gcol] = e;
                }
            }
        }
    }
    if (E16) {
        // 16 passes: 4 rows x 256B coalesced segments per pass
#pragma unroll
        for (int p = 0; p < 16; ++p) {
            int row_l = p * 4 + (lane >> 4);
            int g = lane & 15;
            bf16x8 v = *(const bf16x8*)(&Els[row_l * ELS + g * 8]);
            __builtin_nontemporal_store(
                v, (bf16x8*)&E[(size_t)(rbase + row_l) * VP_ + n0 + g * 8]);
        }
    }
    __builtin_amdgcn_s_barrier();   // Els fully consumed before Pls overwrite

    // epilogue phase 2: LDS transpose reduce of psums (no cross-lane ops).
    // Pls[64][33] f32 per wave: write (row, col=rA), read own row, sum.
    float* Pls = (float*)lds + wid * 64 * 33;
#pragma unroll
    for (int mt = 0; mt < 2; ++mt)
#pragma unroll
        for (int r = 0; r < 16; ++r) {
            int crow = (r & 3) + 8 * (r >> 2) + rhi;
            Pls[(mt * 32 + crow) * 33 + rA] = psum[mt][r];
        }
    const float* prow = Pls + lane * 33;
    f32x4 sv = {};
#pragma unroll
    for (int i = 0; i < 8; ++i) {
        f32x4 v = *(const f32x4*)(prow + i * 4);
        sv[0] += v[0]; sv[1] += v[1]; sv[2] += v[2]; sv[3] += v[3];
    }
    // coalesced partial store: part2[nb][grow]
    part2[(size_t)nb * M_ + rbase + lane] = sv[0] + sv[1] + sv[2] + sv[3];
}

// ---------------------------------------------------------------------------
// finish: rowsum from partials; out[n,0:V] = E*(1-c)/rowsum; out[n,V:] = copy
// 4 blocks per row (V quarter-split); copy part in quarter 3.
template<bool E16>
__global__ __launch_bounds__(256)
void k_finish(const ushort* __restrict__ E, const float* __restrict__ part2,
              const float* __restrict__ cvec, const float* __restrict__ attn,
              const int* __restrict__ ids, float* __restrict__ out)
{
    int n = blockIdx.y;
    int q = blockIdx.x;
    int tid = threadIdx.x;
    float c = cvec[n];
    float* row = out + (size_t)n * NC_;

    __shared__ float ws4[4];
    __shared__ float cp[CV_];
    if (q == 3 && tid < CV_) cp[tid] = 0.f;

    float s = 0.f;
    for (int p = tid; p < NB_; p += 256) s += part2[(size_t)p * M_ + n];
#pragma unroll
    for (int off = 32; off; off >>= 1) s += __shfl_down(s, off);
    if ((tid & 63) == 0) ws4[tid >> 6] = s;
    __syncthreads();
    float rowsum = ws4[0] + ws4[1] + ws4[2] + ws4[3];
    float sc = (1.f - c) / rowsum;

    if (q == 3 && tid < S_)
        atomicAdd(&cp[ids[tid * B_ + (n & (B_ - 1))]],
                  attn[(size_t)n * S_ + tid] * c);

    // V region split in units of 8 floats: 6250 total, quarters of 1564
    int i0 = q * 1564;
    int i1 = min(i0 + 1564, V_ / 8);
    if (E16) {
        const ushort* e = E + (size_t)n * VP_;
        for (int i = i0 + tid; i < i1; i += 256) {
            bf16x8 v = __builtin_nontemporal_load((const bf16x8*)(e + i * 8));
            f32x4 o0, o1;
            o0[0]=(float)v[0]*sc; o0[1]=(float)v[1]*sc; o0[2]=(float)v[2]*sc; o0[3]=(float)v[3]*sc;
            o1[0]=(float)v[4]*sc; o1[1]=(float)v[5]*sc; o1[2]=(float)v[6]*sc; o1[3]=(float)v[7]*sc;
            __builtin_nontemporal_store(o0, (f32x4*)(row + i * 8));
            __builtin_nontemporal_store(o1, (f32x4*)(row + i * 8 + 4));
        }
    } else {
        for (int i = i0 * 2 + tid; i < i1 * 2; i += 256) {
            f32x4 v = *(const f32x4*)(row + i * 4);
            v[0]*=sc; v[1]*=sc; v[2]*=sc; v[3]*=sc;
            *(f32x4*)(row + i * 4) = v;
        }
    }
    if (q == 3) {
        __syncthreads();
        if (tid < CV_) row[V_ + tid] = cp[tid];
    }
}

// ---------------------------------------------------------------------------
extern "C" void kernel_launch(void* const* d_in, const int* in_sizes, int n_in,
                              void* d_out, int out_size, void* d_ws, size_t ws_size,
                              hipStream_t stream)
{
    const float* hidden  = (const float*)d_in[0];
    const float* attn    = (const float*)d_in[1];
    const float* src_map = (const float*)d_in[2];
    const float* W       = (const float*)d_in[3];
    const float* bias    = (const float*)d_in[4];
    const float* w_copy  = (const float*)d_in[5];
    const float* b_copy  = (const float*)d_in[6];
    float* out = (float*)d_out;

    // workspace layout
    size_t off = 0;
    __bf16* Wt = (__bf16*)((char*)d_ws + off); off += (size_t)VP_ * K_ * 2;
    __bf16* Ab = (__bf16*)((char*)d_ws + off); off += (size_t)M_ * K_ * 2;
    float* cvec = (float*)((char*)d_ws + off); off += M_ * 4;
    int*   ids  = (int*)((char*)d_ws + off);   off += 16384;
    float* part2 = (float*)((char*)d_ws + off); off += (size_t)NB_ * M_ * 4;
    ushort* E   = (ushort*)((char*)d_ws + off);
    bool e16 = (off + (size_t)M_ * VP_ * 2) <= ws_size;

    k_pre<<<WT_BLKS + PREP_BLKS + IDS_BLKS, 256, 0, stream>>>(
        W, Wt, hidden, w_copy, b_copy, Ab, cvec, src_map, ids);

    dim3 gg(NMT, NB_);
    dim3 gf(4, M_);
    if (e16) {
        k_gemm_exp<true><<<gg, 256, 0, stream>>>(Ab, Wt, bias, out, E, part2);
        k_finish<true><<<gf, 256, 0, stream>>>(E, part2, cvec, attn, ids, out);
    } else {
        k_gemm_exp<false><<<gg, 256, 0, stream>>>(Ab, Wt, bias, out, E, part2);
        k_finish<false><<<gf, 256, 0, stream>>>((const ushort*)out, part2, cvec, attn, ids, out);
    }
}

// Round 10
// 349.080 us; speedup vs baseline: 1.3859x; 1.3859x over previous
//
#include <hip/hip_runtime.h>
#include <hip/hip_bf16.h>
#include <math.h>

// Problem constants
#define M_ 2048
#define K_ 1024
#define V_ 50000
#define VP_ 50048        // V padded to 128
#define CV_ 120
#define NC_ (V_ + CV_)   // 50120 out row stride
#define S_ 100
#define B_ 32
#define PAD_IDX_ 1

// GEMM tiling: block 256x128, 4 waves stacked in M, wave tile 64x128
// fp8 e4m3 operands, BK=64 (64 BYTES per row -> same staging shape as r9)
#define BM 256
#define BN 128
#define BK 64
#define NKT (K_ / BK)                   // 16 k-steps
#define NB_ (VP_ / BN)                  // 391 N-blocks
#define NMT (M_ / BM)                   // 8 M-blocks
#define NWG_ (NMT * NB_)                // 3128 = 8 * 391
#define WPX_ (NWG_ / 8)                 // 391 (exact)
#define BUFB 24576                      // BYTES per pipeline buf (A 16KB + B 8KB)
#define ELS 136                         // Els row stride (ushorts) = 272B, 16B-aligned
#define PLSS 36                         // Pls row stride (floats) = 144B, 16B-aligned

// merged pre-kernel block ranges
#define WT_BLKS (782 * 16)              // 12512 (64v x 64k tiles)
#define PREP_BLKS (M_ / 4)              // 512
#define IDS_BLKS (((S_ * B_) + 255) / 256) // 13

typedef float f32x4 __attribute__((ext_vector_type(4)));
typedef float f32x16 __attribute__((ext_vector_type(16)));
typedef __bf16 bf16x8 __attribute__((ext_vector_type(8)));
typedef int i32x4 __attribute__((ext_vector_type(4)));
typedef int i32x8 __attribute__((ext_vector_type(8)));
typedef unsigned int u32x2 __attribute__((ext_vector_type(2)));
typedef unsigned short ushort;
typedef unsigned char u8;

__device__ __forceinline__ void async_copy16(const void* g, void* l) {
    __builtin_amdgcn_global_load_lds(
        (const __attribute__((address_space(1))) void*)g,
        (__attribute__((address_space(3))) void*)l, 16, 0, 0);
}
// quarter-wave conflict-free chunk swizzle (verified r4: conflicts -> 0)
#define SIG(row) (((row) >> 1) & 3)

// ---------------------------------------------------------------------------
// merged pre-pass: [0,WT_BLKS) W-transpose->fp8; [WT,+PREP) hidden->fp8 +
// copy gate; [+PREP,+IDS) one-hot -> ids.
__global__ __launch_bounds__(256)
void k_pre(const float* __restrict__ W, u8* __restrict__ Wt,
           const float* __restrict__ hidden, const float* __restrict__ w_copy,
           const float* __restrict__ b_copy, u8* __restrict__ Ab,
           float* __restrict__ cvec, const float* __restrict__ src_map,
           int* __restrict__ ids)
{
    int bx = blockIdx.x;
    int tid = threadIdx.x;
    if (bx < WT_BLKS) {
        // ---- W [K][V] fp32 -> Wt [VP][K] fp8 (64x64 tile transpose)
        __shared__ __align__(16) u8 t8[64][80];
        int v0 = (bx % 782) * 64;
        int k0 = (bx / 782) * 64;
        int kr = tid >> 4;          // 0..15
        int vq = tid & 15;
        int v4 = v0 + vq * 4;
#pragma unroll
        for (int i = 0; i < 4; ++i) {
            int k = k0 + kr + i * 16;
            f32x4 val = {};
            if (v4 < V_) val = *(const f32x4*)(W + (size_t)k * V_ + v4);
#pragma unroll
            for (int c = 0; c < 4; ++c) {
                int r = __builtin_amdgcn_cvt_pk_fp8_f32(val[c], 0.f, 0, 0);
                t8[vq * 4 + c][kr + i * 16] = (u8)r;
            }
        }
        __syncthreads();
        int vr = tid >> 2;          // 0..63
        int q  = tid & 3;           // 16B chunk of the 64B k-run
        i32x4 o = *(const i32x4*)(&t8[vr][q * 16]);
        *(i32x4*)(Wt + (size_t)(v0 + vr) * K_ + k0 + q * 16) = o;
    } else if (bx < WT_BLKS + PREP_BLKS) {
        // ---- hidden->fp8 + copy gate. 1 wave per row.
        int n = (bx - WT_BLKS) * 4 + (tid >> 6);
        int lane = tid & 63;
        const float* h = hidden + (size_t)n * K_;
        u8* arow = Ab + (size_t)n * K_;
        float s = 0.f;
#pragma unroll
        for (int g = 0; g < 2; ++g) {
            int gg = 2 * lane + g;            // granule 0..127 (8 elems)
            f32x4 a = *(const f32x4*)(h + gg * 8);
            f32x4 b = *(const f32x4*)(h + gg * 8 + 4);
            f32x4 wa = *(const f32x4*)(w_copy + gg * 8);
            f32x4 wb = *(const f32x4*)(w_copy + gg * 8 + 4);
            s += a[0]*wa[0] + a[1]*wa[1] + a[2]*wa[2] + a[3]*wa[3]
               + b[0]*wb[0] + b[1]*wb[1] + b[2]*wb[2] + b[3]*wb[3];
            int p0 = __builtin_amdgcn_cvt_pk_fp8_f32(a[0], a[1], 0, 0);
            p0 = __builtin_amdgcn_cvt_pk_fp8_f32(a[2], a[3], p0, 1);
            int p1 = __builtin_amdgcn_cvt_pk_fp8_f32(b[0], b[1], 0, 0);
            p1 = __builtin_amdgcn_cvt_pk_fp8_f32(b[2], b[3], p1, 1);
            u32x2 pk; pk[0] = (unsigned)p0; pk[1] = (unsigned)p1;
            *(u32x2*)(arow + gg * 8) = pk;
        }
#pragma unroll
        for (int off = 32; off; off >>= 1) s += __shfl_down(s, off);
        if (lane == 0) cvec[n] = 1.f / (1.f + __expf(-(s + b_copy[0])));
    } else {
        // ---- one-hot src_map -> integer ids [S*B]
        int i = (bx - WT_BLKS - PREP_BLKS) * 256 + tid;
        if (i < S_ * B_) {
            const float* r = src_map + (size_t)i * CV_;
            int id = 0;
            for (int v = 0; v < CV_; ++v)
                if (r[v] > 0.5f) { id = v; break; }
            ids[i] = id;
        }
    }
}

// ---------------------------------------------------------------------------
// GEMM (MX-fp8): e = exp(A.Wt^T + b) (PAD col->0); bf16 E store; coalesced
// row partials. 3-buf pipeline (unrolled), counted vmcnt(6), raw s_barrier,
// setprio, mfma_scale_32x32x64_f8f6f4 (scales = 1.0), 2-sub-phase body.
template<bool E16>
__global__ __launch_bounds__(256, 2)
void k_gemm_exp(const u8* __restrict__ A, const u8* __restrict__ Bt,
                const float* __restrict__ bias, float* __restrict__ out,
                ushort* __restrict__ E, float* __restrict__ part2)
{
    __shared__ __align__(16) u8 lds8[3 * BUFB];   // 72 KB

    const int tid  = threadIdx.x;
    const int lane = tid & 63;
    const int wid  = tid >> 6;

    // bijective XCD swizzle: 3128 = 8 * 391
    int orig = blockIdx.y * NMT + blockIdx.x;
    int nid  = (orig & 7) * WPX_ + (orig >> 3);
    const int m0 = (nid & 7) * BM;    // m fastest within an XCD's chunk
    const int nb = nid >> 3;
    const int n0 = nb * BN;

    f32x16 acc[2][4] = {};

    // A tile: 256 rows x 64B = 1024 granules (j 0..3); B: 128 rows = 512 (j 0..1)
#define STAGE_A(d, kt)                                                        \
    do {                                                                      \
        _Pragma("unroll")                                                     \
        for (int j = 0; j < 4; ++j) {                                         \
            int g = j * 256 + tid; int row = g >> 2;                          \
            int ch = (g & 3) ^ SIG(row);                                      \
            async_copy16(A + (size_t)(m0 + row) * K_ + (kt) * BK + ch * 16,   \
                         &lds8[(d) * BUFB + (j * 256 + wid * 64) * 16]);      \
        }                                                                     \
    } while (0)
#define STAGE_B(d, kt)                                                        \
    do {                                                                      \
        _Pragma("unroll")                                                     \
        for (int j = 0; j < 2; ++j) {                                         \
            int g = j * 256 + tid; int row = g >> 2;                          \
            int ch = (g & 3) ^ SIG(row);                                      \
            async_copy16(Bt + (size_t)(n0 + row) * K_ + (kt) * BK + ch * 16,  \
                         &lds8[(d) * BUFB + 16384 + (j * 256 + wid * 64) * 16]); \
        }                                                                     \
    } while (0)

    STAGE_A(0, 0); STAGE_B(0, 0);
    STAGE_A(1, 1); STAGE_B(1, 1);

    // 32x32x64 f8f6f4 fragment: row = tile + (lane&31); lane holds 32 k-bytes
    // at k = (lane>>5)*32 (two 16B chunks, SIG-swizzled like staging).
    const int rA  = lane & 31;
    const int kb  = lane >> 5;
    const int sig = (rA >> 1) & 3;

#pragma unroll
    for (int kt = 0; kt < NKT; ++kt) {
        const int cur = kt % 3;
        const int nxt = (kt + 2) % 3;
        __builtin_amdgcn_sched_barrier(0);
        if (kt < NKT - 1) asm volatile("s_waitcnt vmcnt(6)" ::: "memory");
        else              asm volatile("s_waitcnt vmcnt(0)" ::: "memory");
        __builtin_amdgcn_s_barrier();           // S_kt landed; buf(kt-1) reads done
        __builtin_amdgcn_sched_barrier(0);
        const u8* bufA = &lds8[cur * BUFB];
        const u8* bufB = bufA + 16384;
        i32x8 fa[2], fb[4];
        // ---- sub-phase 1: fa + fb[0] reads, A-stage, 2 MFMA
#pragma unroll
        for (int mt = 0; mt < 2; ++mt) {
            int ro = (wid * 64 + mt * 32 + rA) * 64;
            i32x4 lo = *(const i32x4*)(bufA + ro + (((2 * kb + 0) ^ sig) << 4));
            i32x4 hi = *(const i32x4*)(bufA + ro + (((2 * kb + 1) ^ sig) << 4));
            fa[mt] = __builtin_shufflevector(lo, hi, 0, 1, 2, 3, 4, 5, 6, 7);
        }
        {
            int ro = rA * 64;
            i32x4 lo = *(const i32x4*)(bufB + ro + (((2 * kb + 0) ^ sig) << 4));
            i32x4 hi = *(const i32x4*)(bufB + ro + (((2 * kb + 1) ^ sig) << 4));
            fb[0] = __builtin_shufflevector(lo, hi, 0, 1, 2, 3, 4, 5, 6, 7);
        }
        if (kt < NKT - 2) STAGE_A(nxt, kt + 2);
        __builtin_amdgcn_s_setprio(1);
#pragma unroll
        for (int mt = 0; mt < 2; ++mt)
            acc[mt][0] = __builtin_amdgcn_mfma_scale_f32_32x32x64_f8f6f4(
                fa[mt], fb[0], acc[mt][0], 0, 0, 0, 127, 0, 127);
        __builtin_amdgcn_s_setprio(0);
        __builtin_amdgcn_sched_barrier(0);      // keep sub-phase 2 below
        // ---- sub-phase 2: fb[1..3] reads, B-stage, 6 MFMA
#pragma unroll
        for (int nt = 1; nt < 4; ++nt) {
            int ro = (nt * 32 + rA) * 64;
            i32x4 lo = *(const i32x4*)(bufB + ro + (((2 * kb + 0) ^ sig) << 4));
            i32x4 hi = *(const i32x4*)(bufB + ro + (((2 * kb + 1) ^ sig) << 4));
            fb[nt] = __builtin_shufflevector(lo, hi, 0, 1, 2, 3, 4, 5, 6, 7);
        }
        if (kt < NKT - 2) STAGE_B(nxt, kt + 2);
        __builtin_amdgcn_s_setprio(1);
#pragma unroll
        for (int mt = 0; mt < 2; ++mt)
#pragma unroll
            for (int nt = 1; nt < 4; ++nt)
                acc[mt][nt] = __builtin_amdgcn_mfma_scale_f32_32x32x64_f8f6f4(
                    fa[mt], fb[nt], acc[mt][nt], 0, 0, 0, 127, 0, 127);
        __builtin_amdgcn_s_setprio(0);
    }
#undef STAGE_A
#undef STAGE_B

    __builtin_amdgcn_s_barrier();   // main loop fully done before LDS reuse

    // epilogue phase 1: bias + exp + reg psum; stage Els; coalesced E stores.
    // C/D layout (verified m74/m101): col = lane&31, row = (r&3)+8*(r>>2)+4*(lane>>5)
    const int rbase = m0 + wid * 64;
    const int rhi   = (lane >> 5) * 4;
    float psum[2][16];
#pragma unroll
    for (int mt = 0; mt < 2; ++mt)
#pragma unroll
        for (int r = 0; r < 16; ++r) psum[mt][r] = 0.f;
    ushort* Els = (ushort*)lds8 + wid * 64 * ELS;
#pragma unroll
    for (int nt = 0; nt < 4; ++nt) {
        int gcol = n0 + nt * 32 + rA;
        bool live = (gcol < V_) && (gcol != PAD_IDX_);
        float bb = (gcol < V_) ? bias[gcol] : 0.f;
#pragma unroll
        for (int mt = 0; mt < 2; ++mt) {
#pragma unroll
            for (int r = 0; r < 16; ++r) {
                int crow = (r & 3) + 8 * (r >> 2) + rhi;
                float e = live ? __expf(acc[mt][nt][r] + bb) : 0.f;
                psum[mt][r] += e;
                if (E16) {
                    __bf16 h = (__bf16)e;
                    Els[(mt * 32 + crow) * ELS + nt * 32 + rA] = *(const ushort*)&h;
                } else {
                    int grow = rbase + mt * 32 + crow;
                    if (gcol < V_) out[(size_t)grow * NC_ + gcol] = e;
                }
            }
        }
    }
    if (E16) {
        // 16 passes: 4 rows x 256B coalesced segments per pass
#pragma unroll
        for (int p = 0; p < 16; ++p) {
            int row_l = p * 4 + (lane >> 4);
            int g = lane & 15;
            bf16x8 v = *(const bf16x8*)(&Els[row_l * ELS + g * 8]);
            __builtin_nontemporal_store(
                v, (bf16x8*)&E[(size_t)(rbase + row_l) * VP_ + n0 + g * 8]);
        }
    }
    __builtin_amdgcn_s_barrier();   // Els consumed before Pls overwrite

    // epilogue phase 2: LDS transpose reduce of psums (no cross-lane ops).
    float* Pls = (float*)lds8 + wid * 64 * PLSS;
#pragma unroll
    for (int mt = 0; mt < 2; ++mt)
#pragma unroll
        for (int r = 0; r < 16; ++r) {
            int crow = (r & 3) + 8 * (r >> 2) + rhi;
            Pls[(mt * 32 + crow) * PLSS + rA] = psum[mt][r];
        }
    const float* prow = Pls + lane * PLSS;
    f32x4 sv = {};
#pragma unroll
    for (int i = 0; i < 8; ++i) {
        f32x4 v = *(const f32x4*)(prow + i * 4);
        sv[0] += v[0]; sv[1] += v[1]; sv[2] += v[2]; sv[3] += v[3];
    }
    part2[(size_t)nb * M_ + rbase + lane] = sv[0] + sv[1] + sv[2] + sv[3];
}

// ---------------------------------------------------------------------------
// finish: rowsum from partials; out[n,0:V] = E*(1-c)/rowsum; out[n,V:] = copy
// 4 blocks per row (V quarter-split); copy part in quarter 3.
template<bool E16>
__global__ __launch_bounds__(256)
void k_finish(const ushort* __restrict__ E, const float* __restrict__ part2,
              const float* __restrict__ cvec, const float* __restrict__ attn,
              const int* __restrict__ ids, float* __restrict__ out)
{
    int n = blockIdx.y;
    int q = blockIdx.x;
    int tid = threadIdx.x;
    float c = cvec[n];
    float* row = out + (size_t)n * NC_;

    __shared__ float ws4[4];
    __shared__ float cp[CV_];
    if (q == 3 && tid < CV_) cp[tid] = 0.f;

    float s = 0.f;
    for (int p = tid; p < NB_; p += 256) s += part2[(size_t)p * M_ + n];
#pragma unroll
    for (int off = 32; off; off >>= 1) s += __shfl_down(s, off);
    if ((tid & 63) == 0) ws4[tid >> 6] = s;
    __syncthreads();
    float rowsum = ws4[0] + ws4[1] + ws4[2] + ws4[3];
    float sc = (1.f - c) / rowsum;

    if (q == 3 && tid < S_)
        atomicAdd(&cp[ids[tid * B_ + (n & (B_ - 1))]],
                  attn[(size_t)n * S_ + tid] * c);

    // V region split in units of 8 floats: 6250 total, quarters of 1564
    int i0 = q * 1564;
    int i1 = min(i0 + 1564, V_ / 8);
    if (E16) {
        const ushort* e = E + (size_t)n * VP_;
        for (int i = i0 + tid; i < i1; i += 256) {
            bf16x8 v = __builtin_nontemporal_load((const bf16x8*)(e + i * 8));
            f32x4 o0, o1;
            o0[0]=(float)v[0]*sc; o0[1]=(float)v[1]*sc; o0[2]=(float)v[2]*sc; o0[3]=(float)v[3]*sc;
            o1[0]=(float)v[4]*sc; o1[1]=(float)v[5]*sc; o1[2]=(float)v[6]*sc; o1[3]=(float)v[7]*sc;
            __builtin_nontemporal_store(o0, (f32x4*)(row + i * 8));
            __builtin_nontemporal_store(o1, (f32x4*)(row + i * 8 + 4));
        }
    } else {
        for (int i = i0 * 2 + tid; i < i1 * 2; i += 256) {
            f32x4 v = *(const f32x4*)(row + i * 4);
            v[0]*=sc; v[1]*=sc; v[2]*=sc; v[3]*=sc;
            *(f32x4*)(row + i * 4) = v;
        }
    }
    if (q == 3) {
        __syncthreads();
        if (tid < CV_) row[V_ + tid] = cp[tid];
    }
}

// ---------------------------------------------------------------------------
extern "C" void kernel_launch(void* const* d_in, const int* in_sizes, int n_in,
                              void* d_out, int out_size, void* d_ws, size_t ws_size,
                              hipStream_t stream)
{
    const float* hidden  = (const float*)d_in[0];
    const float* attn    = (const float*)d_in[1];
    const float* src_map = (const float*)d_in[2];
    const float* W       = (const float*)d_in[3];
    const float* bias    = (const float*)d_in[4];
    const float* w_copy  = (const float*)d_in[5];
    const float* b_copy  = (const float*)d_in[6];
    float* out = (float*)d_out;

    // workspace layout
    size_t off = 0;
    u8* Wt = (u8*)((char*)d_ws + off); off += (size_t)VP_ * K_;
    u8* Ab = (u8*)((char*)d_ws + off); off += (size_t)M_ * K_;
    float* cvec = (float*)((char*)d_ws + off); off += M_ * 4;
    int*   ids  = (int*)((char*)d_ws + off);   off += 16384;
    float* part2 = (float*)((char*)d_ws + off); off += (size_t)NB_ * M_ * 4;
    ushort* E   = (ushort*)((char*)d_ws + off);
    bool e16 = (off + (size_t)M_ * VP_ * 2) <= ws_size;

    k_pre<<<WT_BLKS + PREP_BLKS + IDS_BLKS, 256, 0, stream>>>(
        W, Wt, hidden, w_copy, b_copy, Ab, cvec, src_map, ids);

    dim3 gg(NMT, NB_);
    dim3 gf(4, M_);
    if (e16) {
        k_gemm_exp<true><<<gg, 256, 0, stream>>>(Ab, Wt, bias, out, E, part2);
        k_finish<true><<<gf, 256, 0, stream>>>(E, part2, cvec, attn, ids, out);
    } else {
        k_gemm_exp<false><<<gg, 256, 0, stream>>>(Ab, Wt, bias, out, E, part2);
        k_finish<false><<<gf, 256, 0, stream>>>((const ushort*)out, part2, cvec, attn, ids, out);
    }
}

// Round 11
// 336.673 us; speedup vs baseline: 1.4370x; 1.0369x over previous
//
#include <hip/hip_runtime.h>
#include <hip/hip_bf16.h>
#include <math.h>

// Problem constants
#define M_ 2048
#define K_ 1024
#define V_ 50000
#define VP_ 50048        // V padded to 128
#define CV_ 120
#define NC_ (V_ + CV_)   // 50120 out row stride
#define S_ 100
#define B_ 32
#define PAD_IDX_ 1

// GEMM tiling: block 256x128, 4 waves stacked in M, wave tile 64x128
// fp8 e4m3 operands, BK=64 (64 BYTES per row)
#define BM 256
#define BN 128
#define BK 64
#define NKT (K_ / BK)                   // 16 k-steps
#define NB_ (VP_ / BN)                  // 391 N-blocks
#define NMT (M_ / BM)                   // 8 M-blocks
#define NWG_ (NMT * NB_)                // 3128 = 8 * 391
#define WPX_ (NWG_ / 8)                 // 391 (exact)
#define BUFB 24576                      // BYTES per pipeline buf (A 16KB + B 8KB)
#define ELS 136                         // Els row stride (ushorts) = 272B, 16B-aligned
#define PLSS 36                         // Pls row stride (floats) = 144B, 16B-aligned
#define ESCALE 0.0625f                  // E stored as e/16 in fp8 (headroom vs 448)

// merged pre-kernel block ranges
#define WT_BLKS (782 * 16)              // 12512 (64v x 64k tiles)
#define PREP_BLKS (M_ / 4)              // 512
#define IDS_BLKS (((S_ * B_) + 255) / 256) // 13

typedef float f32x2 __attribute__((ext_vector_type(2)));
typedef float f32x4 __attribute__((ext_vector_type(4)));
typedef float f32x16 __attribute__((ext_vector_type(16)));
typedef __bf16 bf16x8 __attribute__((ext_vector_type(8)));
typedef int i32x4 __attribute__((ext_vector_type(4)));
typedef int i32x8 __attribute__((ext_vector_type(8)));
typedef unsigned int u32x2 __attribute__((ext_vector_type(2)));
typedef unsigned short ushort;
typedef unsigned char u8;

__device__ __forceinline__ void async_copy16(const void* g, void* l) {
    __builtin_amdgcn_global_load_lds(
        (const __attribute__((address_space(1))) void*)g,
        (__attribute__((address_space(3))) void*)l, 16, 0, 0);
}
// quarter-wave conflict-free chunk swizzle (verified r4: conflicts -> 0)
#define SIG(row) (((row) >> 1) & 3)

// ---------------------------------------------------------------------------
// merged pre-pass: [0,WT_BLKS) W-transpose->fp8; [WT,+PREP) hidden->fp8 +
// copy gate; [+PREP,+IDS) one-hot -> ids.
__global__ __launch_bounds__(256)
void k_pre(const float* __restrict__ W, u8* __restrict__ Wt,
           const float* __restrict__ hidden, const float* __restrict__ w_copy,
           const float* __restrict__ b_copy, u8* __restrict__ Ab,
           float* __restrict__ cvec, const float* __restrict__ src_map,
           int* __restrict__ ids)
{
    int bx = blockIdx.x;
    int tid = threadIdx.x;
    if (bx < WT_BLKS) {
        // ---- W [K][V] fp32 -> Wt [VP][K] fp8 (64x64 tile transpose)
        __shared__ __align__(16) u8 t8[64][80];
        int v0 = (bx % 782) * 64;
        int k0 = (bx / 782) * 64;
        int kr = tid >> 4;          // 0..15
        int vq = tid & 15;
        int v4 = v0 + vq * 4;
#pragma unroll
        for (int i = 0; i < 4; ++i) {
            int k = k0 + kr + i * 16;
            f32x4 val = {};
            if (v4 < V_) val = *(const f32x4*)(W + (size_t)k * V_ + v4);
#pragma unroll
            for (int c = 0; c < 4; ++c) {
                int r = __builtin_amdgcn_cvt_pk_fp8_f32(val[c], 0.f, 0, 0);
                t8[vq * 4 + c][kr + i * 16] = (u8)r;
            }
        }
        __syncthreads();
        int vr = tid >> 2;          // 0..63
        int q  = tid & 3;           // 16B chunk of the 64B k-run
        i32x4 o = *(const i32x4*)(&t8[vr][q * 16]);
        *(i32x4*)(Wt + (size_t)(v0 + vr) * K_ + k0 + q * 16) = o;
    } else if (bx < WT_BLKS + PREP_BLKS) {
        // ---- hidden->fp8 + copy gate. 1 wave per row.
        int n = (bx - WT_BLKS) * 4 + (tid >> 6);
        int lane = tid & 63;
        const float* h = hidden + (size_t)n * K_;
        u8* arow = Ab + (size_t)n * K_;
        float s = 0.f;
#pragma unroll
        for (int g = 0; g < 2; ++g) {
            int gg = 2 * lane + g;            // granule 0..127 (8 elems)
            f32x4 a = *(const f32x4*)(h + gg * 8);
            f32x4 b = *(const f32x4*)(h + gg * 8 + 4);
            f32x4 wa = *(const f32x4*)(w_copy + gg * 8);
            f32x4 wb = *(const f32x4*)(w_copy + gg * 8 + 4);
            s += a[0]*wa[0] + a[1]*wa[1] + a[2]*wa[2] + a[3]*wa[3]
               + b[0]*wb[0] + b[1]*wb[1] + b[2]*wb[2] + b[3]*wb[3];
            int p0 = __builtin_amdgcn_cvt_pk_fp8_f32(a[0], a[1], 0, 0);
            p0 = __builtin_amdgcn_cvt_pk_fp8_f32(a[2], a[3], p0, 1);
            int p1 = __builtin_amdgcn_cvt_pk_fp8_f32(b[0], b[1], 0, 0);
            p1 = __builtin_amdgcn_cvt_pk_fp8_f32(b[2], b[3], p1, 1);
            u32x2 pk; pk[0] = (unsigned)p0; pk[1] = (unsigned)p1;
            *(u32x2*)(arow + gg * 8) = pk;
        }
#pragma unroll
        for (int off = 32; off; off >>= 1) s += __shfl_down(s, off);
        if (lane == 0) cvec[n] = 1.f / (1.f + __expf(-(s + b_copy[0])));
    } else {
        // ---- one-hot src_map -> integer ids [S*B]
        int i = (bx - WT_BLKS - PREP_BLKS) * 256 + tid;
        if (i < S_ * B_) {
            const float* r = src_map + (size_t)i * CV_;
            int id = 0;
            for (int v = 0; v < CV_; ++v)
                if (r[v] > 0.5f) { id = v; break; }
            ids[i] = id;
        }
    }
}

// ---------------------------------------------------------------------------
// GEMM (MX-fp8): e = exp(A.Wt^T + b) (PAD col->0); fp8 E store (e/16);
// coalesced row partials. 3-buf pipeline (unrolled), counted vmcnt(6),
// raw s_barrier, setprio, mfma_scale_32x32x64_f8f6f4, 2-sub-phase body.
template<bool E8P>
__global__ __launch_bounds__(256, 2)
void k_gemm_exp(const u8* __restrict__ A, const u8* __restrict__ Bt,
                const float* __restrict__ bias, float* __restrict__ out,
                u8* __restrict__ E8, float* __restrict__ part2)
{
    __shared__ __align__(16) u8 lds8[3 * BUFB];   // 72 KB

    const int tid  = threadIdx.x;
    const int lane = tid & 63;
    const int wid  = tid >> 6;

    // bijective XCD swizzle: 3128 = 8 * 391
    int orig = blockIdx.y * NMT + blockIdx.x;
    int nid  = (orig & 7) * WPX_ + (orig >> 3);
    const int m0 = (nid & 7) * BM;    // m fastest within an XCD's chunk
    const int nb = nid >> 3;
    const int n0 = nb * BN;

    f32x16 acc[2][4] = {};

    // A tile: 256 rows x 64B = 1024 granules (j 0..3); B: 128 rows = 512 (j 0..1)
#define STAGE_A(d, kt)                                                        \
    do {                                                                      \
        _Pragma("unroll")                                                     \
        for (int j = 0; j < 4; ++j) {                                         \
            int g = j * 256 + tid; int row = g >> 2;                          \
            int ch = (g & 3) ^ SIG(row);                                      \
            async_copy16(A + (size_t)(m0 + row) * K_ + (kt) * BK + ch * 16,   \
                         &lds8[(d) * BUFB + (j * 256 + wid * 64) * 16]);      \
        }                                                                     \
    } while (0)
#define STAGE_B(d, kt)                                                        \
    do {                                                                      \
        _Pragma("unroll")                                                     \
        for (int j = 0; j < 2; ++j) {                                         \
            int g = j * 256 + tid; int row = g >> 2;                          \
            int ch = (g & 3) ^ SIG(row);                                      \
            async_copy16(Bt + (size_t)(n0 + row) * K_ + (kt) * BK + ch * 16,  \
                         &lds8[(d) * BUFB + 16384 + (j * 256 + wid * 64) * 16]); \
        }                                                                     \
    } while (0)

    STAGE_A(0, 0); STAGE_B(0, 0);
    STAGE_A(1, 1); STAGE_B(1, 1);

    // 32x32x64 f8f6f4 fragment: row = tile + (lane&31); lane holds 32 k-bytes
    // at k = (lane>>5)*32 (two 16B chunks, SIG-swizzled like staging).
    const int rA  = lane & 31;
    const int kb  = lane >> 5;
    const int sig = (rA >> 1) & 3;

#pragma unroll
    for (int kt = 0; kt < NKT; ++kt) {
        const int cur = kt % 3;
        const int nxt = (kt + 2) % 3;
        __builtin_amdgcn_sched_barrier(0);
        if (kt < NKT - 1) asm volatile("s_waitcnt vmcnt(6)" ::: "memory");
        else              asm volatile("s_waitcnt vmcnt(0)" ::: "memory");
        __builtin_amdgcn_s_barrier();           // S_kt landed; buf(kt-1) reads done
        __builtin_amdgcn_sched_barrier(0);
        const u8* bufA = &lds8[cur * BUFB];
        const u8* bufB = bufA + 16384;
        i32x8 fa[2], fb[4];
        // ---- sub-phase 1: fa + fb[0] reads, A-stage, 2 MFMA
#pragma unroll
        for (int mt = 0; mt < 2; ++mt) {
            int ro = (wid * 64 + mt * 32 + rA) * 64;
            i32x4 lo = *(const i32x4*)(bufA + ro + (((2 * kb + 0) ^ sig) << 4));
            i32x4 hi = *(const i32x4*)(bufA + ro + (((2 * kb + 1) ^ sig) << 4));
            fa[mt] = __builtin_shufflevector(lo, hi, 0, 1, 2, 3, 4, 5, 6, 7);
        }
        {
            int ro = rA * 64;
            i32x4 lo = *(const i32x4*)(bufB + ro + (((2 * kb + 0) ^ sig) << 4));
            i32x4 hi = *(const i32x4*)(bufB + ro + (((2 * kb + 1) ^ sig) << 4));
            fb[0] = __builtin_shufflevector(lo, hi, 0, 1, 2, 3, 4, 5, 6, 7);
        }
        if (kt < NKT - 2) STAGE_A(nxt, kt + 2);
        __builtin_amdgcn_s_setprio(1);
#pragma unroll
        for (int mt = 0; mt < 2; ++mt)
            acc[mt][0] = __builtin_amdgcn_mfma_scale_f32_32x32x64_f8f6f4(
                fa[mt], fb[0], acc[mt][0], 0, 0, 0, 127, 0, 127);
        __builtin_amdgcn_s_setprio(0);
        __builtin_amdgcn_sched_barrier(0);      // keep sub-phase 2 below
        // ---- sub-phase 2: fb[1..3] reads, B-stage, 6 MFMA
#pragma unroll
        for (int nt = 1; nt < 4; ++nt) {
            int ro = (nt * 32 + rA) * 64;
            i32x4 lo = *(const i32x4*)(bufB + ro + (((2 * kb + 0) ^ sig) << 4));
            i32x4 hi = *(const i32x4*)(bufB + ro + (((2 * kb + 1) ^ sig) << 4));
            fb[nt] = __builtin_shufflevector(lo, hi, 0, 1, 2, 3, 4, 5, 6, 7);
        }
        if (kt < NKT - 2) STAGE_B(nxt, kt + 2);
        __builtin_amdgcn_s_setprio(1);
#pragma unroll
        for (int mt = 0; mt < 2; ++mt)
#pragma unroll
            for (int nt = 1; nt < 4; ++nt)
                acc[mt][nt] = __builtin_amdgcn_mfma_scale_f32_32x32x64_f8f6f4(
                    fa[mt], fb[nt], acc[mt][nt], 0, 0, 0, 127, 0, 127);
        __builtin_amdgcn_s_setprio(0);
    }
#undef STAGE_A
#undef STAGE_B

    __builtin_amdgcn_s_barrier();   // main loop fully done before LDS reuse

    // epilogue phase 1: bias + exp + reg psum; stage Els (bf16); fp8 E stores.
    // C/D layout (verified m74/m101): col = lane&31, row = (r&3)+8*(r>>2)+4*(lane>>5)
    const int rbase = m0 + wid * 64;
    const int rhi   = (lane >> 5) * 4;
    float psum[2][16];
#pragma unroll
    for (int mt = 0; mt < 2; ++mt)
#pragma unroll
        for (int r = 0; r < 16; ++r) psum[mt][r] = 0.f;
    ushort* Els = (ushort*)lds8 + wid * 64 * ELS;
#pragma unroll
    for (int nt = 0; nt < 4; ++nt) {
        int gcol = n0 + nt * 32 + rA;
        bool live = (gcol < V_) && (gcol != PAD_IDX_);
        float bb = (gcol < V_) ? bias[gcol] : 0.f;
#pragma unroll
        for (int mt = 0; mt < 2; ++mt) {
#pragma unroll
            for (int r = 0; r < 16; ++r) {
                int crow = (r & 3) + 8 * (r >> 2) + rhi;
                float e = live ? __expf(acc[mt][nt][r] + bb) : 0.f;
                psum[mt][r] += e;
                if (E8P) {
                    __bf16 h = (__bf16)e;
                    Els[(mt * 32 + crow) * ELS + nt * 32 + rA] = *(const ushort*)&h;
                } else {
                    int grow = rbase + mt * 32 + crow;
                    if (gcol < V_) out[(size_t)grow * NC_ + gcol] = e;
                }
            }
        }
    }
    if (E8P) {
        // 16 passes: 4 rows x 128B coalesced fp8 segments per pass (e/16)
#pragma unroll
        for (int p = 0; p < 16; ++p) {
            int row_l = p * 4 + (lane >> 4);
            int g = lane & 15;
            bf16x8 v = *(const bf16x8*)(&Els[row_l * ELS + g * 8]);
            float f0 = (float)v[0] * ESCALE, f1 = (float)v[1] * ESCALE;
            float f2 = (float)v[2] * ESCALE, f3 = (float)v[3] * ESCALE;
            float f4 = (float)v[4] * ESCALE, f5 = (float)v[5] * ESCALE;
            float f6 = (float)v[6] * ESCALE, f7 = (float)v[7] * ESCALE;
            int w0 = __builtin_amdgcn_cvt_pk_fp8_f32(f0, f1, 0, 0);
            w0 = __builtin_amdgcn_cvt_pk_fp8_f32(f2, f3, w0, 1);
            int w1 = __builtin_amdgcn_cvt_pk_fp8_f32(f4, f5, 0, 0);
            w1 = __builtin_amdgcn_cvt_pk_fp8_f32(f6, f7, w1, 1);
            u32x2 pk; pk[0] = (unsigned)w0; pk[1] = (unsigned)w1;
            __builtin_nontemporal_store(
                pk, (u32x2*)&E8[(size_t)(rbase + row_l) * VP_ + n0 + g * 8]);
        }
    }
    __builtin_amdgcn_s_barrier();   // Els consumed before Pls overwrite

    // epilogue phase 2: LDS transpose reduce of psums (no cross-lane ops).
    float* Pls = (float*)lds8 + wid * 64 * PLSS;
#pragma unroll
    for (int mt = 0; mt < 2; ++mt)
#pragma unroll
        for (int r = 0; r < 16; ++r) {
            int crow = (r & 3) + 8 * (r >> 2) + rhi;
            Pls[(mt * 32 + crow) * PLSS + rA] = psum[mt][r];
        }
    const float* prow = Pls + lane * PLSS;
    f32x4 sv = {};
#pragma unroll
    for (int i = 0; i < 8; ++i) {
        f32x4 v = *(const f32x4*)(prow + i * 4);
        sv[0] += v[0]; sv[1] += v[1]; sv[2] += v[2]; sv[3] += v[3];
    }
    part2[(size_t)nb * M_ + rbase + lane] = sv[0] + sv[1] + sv[2] + sv[3];
}

// ---------------------------------------------------------------------------
// finish: rowsum from partials; out[n,0:V] = fp8decode(E8)*16*(1-c)/rowsum;
// out[n,V:] = copy part. 4 blocks per row (V quarter-split); copy in q==3.
template<bool E8P>
__global__ __launch_bounds__(256)
void k_finish(const u8* __restrict__ E8, const float* __restrict__ part2,
              const float* __restrict__ cvec, const float* __restrict__ attn,
              const int* __restrict__ ids, float* __restrict__ out)
{
    int n = blockIdx.y;
    int q = blockIdx.x;
    int tid = threadIdx.x;
    float c = cvec[n];
    float* row = out + (size_t)n * NC_;

    __shared__ float ws4[4];
    __shared__ float cp[CV_];
    if (q == 3 && tid < CV_) cp[tid] = 0.f;

    float s = 0.f;
    for (int p = tid; p < NB_; p += 256) s += part2[(size_t)p * M_ + n];
#pragma unroll
    for (int off = 32; off; off >>= 1) s += __shfl_down(s, off);
    if ((tid & 63) == 0) ws4[tid >> 6] = s;
    __syncthreads();
    float rowsum = ws4[0] + ws4[1] + ws4[2] + ws4[3];
    float sc16 = (1.f - c) / rowsum * 16.f;

    if (q == 3 && tid < S_)
        atomicAdd(&cp[ids[tid * B_ + (n & (B_ - 1))]],
                  attn[(size_t)n * S_ + tid] * c);

    // V region split in units of 8 values: 6250 total, quarters of 1563
    int i0 = q * 1563;
    int i1 = min(i0 + 1563, V_ / 8);
    if (E8P) {
        const u8* e8 = E8 + (size_t)n * VP_;
        for (int i = i0 + tid; i < i1; i += 256) {
            u32x2 w = __builtin_nontemporal_load((const u32x2*)(e8 + i * 8));
            f32x2 a0 = __builtin_amdgcn_cvt_pk_f32_fp8(w[0], false);
            f32x2 a1 = __builtin_amdgcn_cvt_pk_f32_fp8(w[0], true);
            f32x2 a2 = __builtin_amdgcn_cvt_pk_f32_fp8(w[1], false);
            f32x2 a3 = __builtin_amdgcn_cvt_pk_f32_fp8(w[1], true);
            f32x4 o0, o1;
            o0[0] = a0[0] * sc16; o0[1] = a0[1] * sc16;
            o0[2] = a1[0] * sc16; o0[3] = a1[1] * sc16;
            o1[0] = a2[0] * sc16; o1[1] = a2[1] * sc16;
            o1[2] = a3[0] * sc16; o1[3] = a3[1] * sc16;
            __builtin_nontemporal_store(o0, (f32x4*)(row + i * 8));
            __builtin_nontemporal_store(o1, (f32x4*)(row + i * 8 + 4));
        }
    } else {
        float scp = sc16 * ESCALE;   // plain (1-c)/rowsum
        for (int i = i0 * 2 + tid; i < i1 * 2; i += 256) {
            f32x4 v = *(const f32x4*)(row + i * 4);
            v[0]*=scp; v[1]*=scp; v[2]*=scp; v[3]*=scp;
            *(f32x4*)(row + i * 4) = v;
        }
    }
    if (q == 3) {
        __syncthreads();
        if (tid < CV_) row[V_ + tid] = cp[tid];
    }
}

// ---------------------------------------------------------------------------
extern "C" void kernel_launch(void* const* d_in, const int* in_sizes, int n_in,
                              void* d_out, int out_size, void* d_ws, size_t ws_size,
                              hipStream_t stream)
{
    const float* hidden  = (const float*)d_in[0];
    const float* attn    = (const float*)d_in[1];
    const float* src_map = (const float*)d_in[2];
    const float* W       = (const float*)d_in[3];
    const float* bias    = (const float*)d_in[4];
    const float* w_copy  = (const float*)d_in[5];
    const float* b_copy  = (const float*)d_in[6];
    float* out = (float*)d_out;

    // workspace layout
    size_t off = 0;
    u8* Wt = (u8*)((char*)d_ws + off); off += (size_t)VP_ * K_;
    u8* Ab = (u8*)((char*)d_ws + off); off += (size_t)M_ * K_;
    float* cvec = (float*)((char*)d_ws + off); off += M_ * 4;
    int*   ids  = (int*)((char*)d_ws + off);   off += 16384;
    float* part2 = (float*)((char*)d_ws + off); off += (size_t)NB_ * M_ * 4;
    u8* E8 = (u8*)((char*)d_ws + off);
    bool e8p = (off + (size_t)M_ * VP_) <= ws_size;

    k_pre<<<WT_BLKS + PREP_BLKS + IDS_BLKS, 256, 0, stream>>>(
        W, Wt, hidden, w_copy, b_copy, Ab, cvec, src_map, ids);

    dim3 gg(NMT, NB_);
    dim3 gf(4, M_);
    if (e8p) {
        k_gemm_exp<true><<<gg, 256, 0, stream>>>(Ab, Wt, bias, out, E8, part2);
        k_finish<true><<<gf, 256, 0, stream>>>(E8, part2, cvec, attn, ids, out);
    } else {
        k_gemm_exp<false><<<gg, 256, 0, stream>>>(Ab, Wt, bias, out, E8, part2);
        k_finish<false><<<gf, 256, 0, stream>>>((const u8*)out, part2, cvec, attn, ids, out);
    }
}